// Round 16
// baseline (571.261 us; speedup 1.0000x reference)
//
#include <hip/hip_runtime.h>
#include <math.h>

#define LB __launch_bounds__(256)
#define LB512 __launch_bounds__(512)
#define LB64 __launch_bounds__(64)

// B=8, DIM=128, C=32, DI=64, H=W=64, L=4096, K=4, N=16, R=2, G=64 chunks of 64
#define LOG2E 1.44269504088896340736f
static __device__ __forceinline__ float silu_f(float x){ return x / (1.f + __expf(-x)); }
static __device__ __forceinline__ float softplus_f(float x){
    return (x > 20.f) ? x : __logf(1.f + __expf(x));
}

struct AxialArgs { const float* w[18]; };

// ---------------- axial depthwise (3 chunks) + fused chunk-4 BN/ReLU passthrough -------
__global__ LB void axial_kernel(const float* __restrict__ x, AxialArgs args,
    float* __restrict__ acc,
    const float* __restrict__ bn_g, const float* __restrict__ bn_b,
    const float* __restrict__ bn_m, const float* __restrict__ bn_v,
    float* __restrict__ out)
{
    __shared__ float s0[4096];
    __shared__ float s1[4096];
    if (blockIdx.x >= 768){
        const int gid = (blockIdx.x - 768)*256 + threadIdx.x;
        const int e = gid*4;
        const int l = e & 4095, bc = e >> 12;
        const int c = bc & 31, b = bc >> 5;
        const int ch = 96 + c;
        const size_t idx = ((size_t)b*128+ch)*4096 + l;
        float4 v = *(const float4*)&x[idx];
        const float sc = rsqrtf(bn_v[ch]+1e-5f)*bn_g[ch];
        const float mb = bn_m[ch], bbv = bn_b[ch];
        v.x = fmaxf((v.x-mb)*sc+bbv, 0.f);
        v.y = fmaxf((v.y-mb)*sc+bbv, 0.f);
        v.z = fmaxf((v.z-mb)*sc+bbv, 0.f);
        v.w = fmaxf((v.w-mb)*sc+bbv, 0.f);
        *(float4*)&out[idx] = v;
        return;
    }
    const int chunk = blockIdx.x >> 8;
    const int bc = blockIdx.x & 255;      // b*32 + c
    const int b = bc >> 5, c = bc & 31;
    const int dil = chunk + 1;
    const float* mh_w = args.w[chunk*6+0];
    const float* mh_b = args.w[chunk*6+1];
    const float* mw_w = args.w[chunk*6+2];
    const float* mw_b = args.w[chunk*6+3];
    const float* cw   = args.w[chunk*6+4];
    const float* cb   = args.w[chunk*6+5];
    const int tid = threadIdx.x;
    const float* xin = x + ((size_t)(b*128 + chunk*32 + c)) * 4096;
    float orig[16];
    #pragma unroll
    for (int kk=0;kk<16;++kk){ float v=xin[tid+kk*256]; orig[kk]=v; s0[tid+kk*256]=v; }
    __syncthreads();

    float w7[7];
    #pragma unroll
    for (int t=0;t<7;++t) w7[t]=mw_w[c*7+t];
    float bias = mw_b[c];
    float v[16];
    #pragma unroll
    for (int kk=0;kk<16;++kk){
        int p=tid+kk*256, i=p>>6, j=p&63;
        float s=bias;
        #pragma unroll
        for (int t=0;t<7;++t){ int jj=j+(t-3)*dil; if (jj>=0&&jj<64) s+=s0[i*64+jj]*w7[t]; }
        v[kk]=s;
    }
    #pragma unroll
    for (int kk=0;kk<16;++kk) s1[tid+kk*256]=v[kk];
    __syncthreads();

    #pragma unroll
    for (int t=0;t<7;++t) w7[t]=mh_w[c*7+t];
    bias = mh_b[c];
    #pragma unroll
    for (int kk=0;kk<16;++kk){
        int p=tid+kk*256, i=p>>6, j=p&63;
        float s=bias;
        #pragma unroll
        for (int t=0;t<7;++t){ int ii=i+(t-3)*dil; if (ii>=0&&ii<64) s+=s1[ii*64+j]*w7[t]; }
        v[kk]=s;
    }
    __syncthreads();
    #pragma unroll
    for (int kk=0;kk<16;++kk) s0[tid+kk*256]=v[kk];
    __syncthreads();

    float w9[9];
    #pragma unroll
    for (int t=0;t<9;++t) w9[t]=cw[c*9+t];
    bias = cb[c];
    float* aout = acc + (size_t)chunk*1048576 + ((size_t)(b*32+c))*4096;
    #pragma unroll
    for (int kk=0;kk<16;++kk){
        int p=tid+kk*256, i=p>>6, j=p&63;
        float s=bias;
        #pragma unroll
        for (int a=0;a<3;++a){
            int ii=i+(a-1)*dil; if (ii<0||ii>=64) continue;
            #pragma unroll
            for (int bb2=0;bb2<3;++bb2){
                int jj=j+(bb2-1)*dil; if (jj<0||jj>=64) continue;
                s += s0[ii*64+jj]*w9[a*3+bb2];
            }
        }
        aout[p] = s + orig[kk];
    }
}

// ---------------- LN(C=32) + in_proj (32 -> 128), split xc / z -------------------------
__global__ LB512 void lnproj_kernel(const float* __restrict__ acc, int ch0, size_t cs,
    const float* __restrict__ ln_w, const float* __restrict__ ln_b,
    const float* __restrict__ in_proj_w,
    float* __restrict__ xc, float* __restrict__ z)
{
    __shared__ float s_a[32*65];
    const int cl = blockIdx.x >> 9;
    const int local = blockIdx.x & 511;
    const int chunk = ch0 + cl;
    const int b = local >> 6, lt = local & 63;
    const int l0 = lt*64;
    const int tid = threadIdx.x;
    const float* ab = acc + (size_t)chunk*1048576 + (size_t)b*32*4096 + l0;
    for (int i=tid;i<2048;i+=512){ int c=i>>6, j=i&63; s_a[c*65+j]=ab[(size_t)c*4096 + j]; }
    __syncthreads();
    const int l = tid & 63;
    const int g = __builtin_amdgcn_readfirstlane(tid >> 6);
    float v[32];
    float mu=0.f;
    #pragma unroll
    for (int c=0;c<32;++c){ v[c]=s_a[c*65+l]; mu+=v[c]; }
    mu *= (1.f/32.f);
    float var=0.f;
    #pragma unroll
    for (int c=0;c<32;++c){ float d2=v[c]-mu; var+=d2*d2; }
    var *= (1.f/32.f);
    float rs = rsqrtf(var+1e-5f);
    #pragma unroll
    for (int c=0;c<32;++c) v[c] = (v[c]-mu)*rs*ln_w[c] + ln_b[c];
    float* xcp = xc + (size_t)cl*cs + (size_t)b*64*4096 + l0 + l;
    float* zp  = z  + (size_t)cl*cs + (size_t)b*64*4096 + l0 + l;
    for (int e=g*16; e<g*16+16; ++e){
        const float* wr = in_proj_w + e*32;   // uniform rows -> scalar loads
        float s=0.f;
        #pragma unroll
        for (int c=0;c<32;++c) s += wr[c]*v[c];
        if (e<64) xcp[(size_t)e*4096]=s; else zp[(size_t)(e-64)*4096]=s;
    }
}

// ---------------- 3x3 dwconv (dil=1) + SiLU, fused transpose output --------------------
__global__ LB void conv3_kernel(const float* __restrict__ xc, size_t cs,
    const float* __restrict__ conv_w, const float* __restrict__ conv_b,
    float* __restrict__ xconv, float* __restrict__ xconvT)
{
    __shared__ float s0[4096];
    __shared__ float s1[64*65];
    const int cl = blockIdx.x >> 9;
    const int bd = blockIdx.x & 511;  // b*64 + d
    const int d = bd & 63;
    const int tid = threadIdx.x;
    const float* in = xc + (size_t)cl*cs + (size_t)bd*4096;
    #pragma unroll
    for (int kk=0;kk<16;++kk) s0[tid+kk*256]=in[tid+kk*256];
    __syncthreads();
    float w9[9];
    #pragma unroll
    for (int t=0;t<9;++t) w9[t]=conv_w[d*9+t];
    float bias = conv_b[d];
    float* outp = xconv + (size_t)cl*cs + (size_t)bd*4096;
    #pragma unroll
    for (int kk=0;kk<16;++kk){
        int p=tid+kk*256, i=p>>6, j=p&63;
        float s=bias;
        #pragma unroll
        for (int a=0;a<3;++a){
            int ii=i+a-1; if (ii<0||ii>=64) continue;
            #pragma unroll
            for (int bb2=0;bb2<3;++bb2){
                int jj=j+bb2-1; if (jj<0||jj>=64) continue;
                s += s0[ii*64+jj]*w9[a*3+bb2];
            }
        }
        s = silu_f(s);
        outp[p]=s;
        s1[i*65+j]=s;
    }
    __syncthreads();
    float* outT = xconvT + (size_t)cl*cs + (size_t)bd*4096;
    #pragma unroll
    for (int kk=0;kk<16;++kk){ int p=tid+kk*256; outT[p] = s1[(p&63)*65 + (p>>6)]; }
}

// ---------------- fused x_proj + dt_proj + softplus + scan phase 1 ---------------------
// grid nch*2048 (1 tile/block); GEMM scatters into PADDED temps (conflict-free);
// shared dlt pass (softplus once per (t,d)); scan fully unrolled (immediate LDS offsets)
__global__ LB void projscan1_kernel(const float* __restrict__ xconv, const float* __restrict__ xconvT,
    size_t cs,
    const float* __restrict__ x_proj_w, const float* __restrict__ dt_proj_w,
    const float* __restrict__ dt_proj_b, const float* __restrict__ A_log,
    float* __restrict__ Bsb, float* __restrict__ Csb, float* __restrict__ dts_g,
    float* __restrict__ Ssum, float* __restrict__ hloc)
{
    __shared__ float s_x[64*65];                  // [t][d] u; overwritten with du
    __shared__ float s_dlt[64*65];                // scratch Bp/Cp; later dlt [t][d]
    __shared__ __align__(16) float s_B[1024];     // packed [t][16] for scan broadcast
    __shared__ __align__(8) float s_dts[128];     // [t][2]
    float* s_Bp = s_dlt;                          // padded [t][17]
    float* s_Cp = s_dlt + 1152;                   // padded [t][17]
    const int cl = blockIdx.x >> 11;
    const int blkL = blockIdx.x & 2047;
    const int g = blkL & 63, bk = blkL >> 6;
    const int k = bk & 3, b = bk >> 2;
    const int tid = threadIdx.x;
    const int t0 = g*64;
    const float* src = ((k & 1) ? xconvT : xconv) + (size_t)cl*cs;
    const float* sb = src + (size_t)b*64*4096;
    // float4 staging: 4 rows x 256B per wave-instruction
    #pragma unroll
    for (int it=0; it<4; ++it){
        const int i4 = tid + it*256;           // 0..1023
        const int d = i4 >> 4, jq = (i4 & 15)*4;
        if (k & 2){
            float4 r = *(const float4*)(sb + (size_t)d*4096 + (4092 - t0 - jq));
            s_x[(jq+3)*65 + d] = r.x;
            s_x[(jq+2)*65 + d] = r.y;
            s_x[(jq+1)*65 + d] = r.z;
            s_x[(jq+0)*65 + d] = r.w;
        } else {
            float4 r = *(const float4*)(sb + (size_t)d*4096 + t0 + jq);
            s_x[(jq+0)*65 + d] = r.x;
            s_x[(jq+1)*65 + d] = r.y;
            s_x[(jq+2)*65 + d] = r.z;
            s_x[(jq+3)*65 + d] = r.w;
        }
    }
    __syncthreads();

    // ---- proj GEMM: q-group owns 9 (or 7) rows of x_proj_w; padded scatter ----
    {
        const int t = tid & 63;
        const int q = __builtin_amdgcn_readfirstlane(tid >> 6);
        const float* wp = x_proj_w + k*2176;
        float acc9[9];
        #pragma unroll
        for (int r=0;r<9;++r) acc9[r]=0.f;
        const int r0 = q*9;
        const int nr = (q==3)?7:9;
        for (int ch=0; ch<4; ++ch){
            float xv[16];
            #pragma unroll
            for (int i=0;i<16;++i) xv[i] = s_x[t*65 + ch*16 + i];
            #pragma unroll
            for (int r=0;r<9;++r){
                if (r < nr){
                    const float* wr = wp + (r0+r)*64 + ch*16;   // uniform -> scalar loads
                    float s=0.f;
                    #pragma unroll
                    for (int i=0;i<16;++i) s += wr[i]*xv[i];
                    acc9[r] += s;
                }
            }
        }
        #pragma unroll
        for (int r=0;r<9;++r){
            if (r<nr){
                int row = r0 + r;
                if (row < 2)       s_dts[t*2 + row]       = acc9[r];
                else if (row < 18) s_Bp[t*17 + (row-2)]   = acc9[r];
                else               s_Cp[t*17 + (row-18)]  = acc9[r];
            }
        }
    }
    __syncthreads();

    // ---- flush B/C/dts (coalesced, packed) + repack B for scan broadcast ----
    {
        float* BsbC = Bsb + (size_t)cl*cs;
        float* CsbC = Csb + (size_t)cl*cs;
        const size_t tb = (size_t)blkL*1024;
        for (int i=tid;i<1024;i+=256){
            int a = (i>>4)*17 + (i&15);
            float bv = s_Bp[a], cv = s_Cp[a];
            BsbC[tb+i]=bv; CsbC[tb+i]=cv;
            s_B[i]=bv;
        }
        if (tid<128) (dts_g + (size_t)cl*cs)[(size_t)blkL*128 + tid] = s_dts[tid];
    }
    __syncthreads();   // Bp/Cp reads done before dlt overwrite

    // ---- shared dlt pass: softplus once per (t,d); du in place ----
    {
        const int d_ = tid & 63, part = tid >> 6;
        const float w0 = dt_proj_w[k*128 + d_*2], w1 = dt_proj_w[k*128 + d_*2 + 1];
        const float bb = dt_proj_b[k*64 + d_];
        #pragma unroll
        for (int i=0;i<16;++i){
            const int t = part*16 + i;
            float dlt = softplus_f(s_dts[t*2]*w0 + s_dts[t*2+1]*w1 + bb);
            s_dlt[t*65 + d_] = dlt;
            s_x[t*65 + d_] *= dlt;        // du
        }
    }
    __syncthreads();

    // ---- local scan: lane = d, wave w owns n-quad w; FULL unroll -> immediate offsets --
    const int d = tid & 63;
    const int w = __builtin_amdgcn_readfirstlane(tid >> 6);
    float4 Av = *(const float4*)(A_log + ((size_t)(k*64+d)*16 + w*4));
    const float A0 = -__expf(Av.x)*LOG2E, A1 = -__expf(Av.y)*LOG2E,
                A2 = -__expf(Av.z)*LOG2E, A3 = -__expf(Av.w)*LOG2E;
    float h0=0,h1=0,h2=0,h3=0, S=0.f;
    #pragma unroll
    for (int t=0;t<64;++t){
        float dlt = s_dlt[t*65+d];
        float du  = s_x[t*65+d];
        S += dlt;
        float4 Bv = *(const float4*)&s_B[t*16 + w*4];   // uniform addr -> broadcast
        h0 = h0*exp2f(dlt*A0) + du*Bv.x;
        h1 = h1*exp2f(dlt*A1) + du*Bv.y;
        h2 = h2*exp2f(dlt*A2) + du*Bv.z;
        h3 = h3*exp2f(dlt*A3) + du*Bv.w;
    }
    if (w == 0) (Ssum + (size_t)cl*cs)[(size_t)blkL*64 + d] = S;
    ((float4*)(hloc + (size_t)cl*cs))[(size_t)blkL*256 + d*4 + w] = make_float4(h0,h1,h2,h3);
}

// ---------------- scan phase 2: chunk combine; Aprod = exp2(A * S_chunk) ---------------
// grid nch*512 x 64 thr (1 wave / block, all CUs covered)
__global__ LB64 void scan2_kernel(const float* __restrict__ Ssum, size_t cs,
    const float* __restrict__ hloc, const float* __restrict__ A_log,
    float* __restrict__ hin)
{
    const int cl = blockIdx.x >> 9;
    const int j = (blockIdx.x & 511)*64 + threadIdx.x;   // 0..32767 : (b,k,dn)
    const int bk = j >> 10, dn = j & 1023;
    const int k = bk & 3, d = dn >> 4, n = dn & 15;
    const float* SsC = Ssum + (size_t)cl*cs;
    const float* hlC = hloc + (size_t)cl*cs;
    float* hinC = hin + (size_t)cl*cs;
    const float A = -__expf(A_log[(size_t)(k*64+d)*16 + n]) * LOG2E;
    float h = 0.f;
    #pragma unroll 4
    for (int g=0; g<64; ++g){
        const size_t o = ((size_t)bk*64 + g)*1024 + dn;
        hinC[o] = h;
        float S = SsC[((size_t)bk*64 + g)*64 + d];
        h = exp2f(A*S)*h + hlC[o];
    }
}

// ---------------- scan phase 3: 1 wave per tile; B/C/dts via SCALAR loads --------------
// y staged in s_y, flushed coalesced; flipped dirs (k>=2) atomicAdd into fwd planes
// outy layout: [cl][b][plane=k&1][64 d][4096]  (memset to 0 before launch)
__global__ LB void scan3_kernel(const float* __restrict__ xconv, const float* __restrict__ xconvT,
    size_t cs,
    const float* __restrict__ Bsb, const float* __restrict__ Csb,
    const float* __restrict__ dts_g,
    const float* __restrict__ dt_proj_w, const float* __restrict__ dt_proj_b,
    const float* __restrict__ A_log, const float* __restrict__ Dp,
    const float* __restrict__ hin, float* __restrict__ outy)
{
    __shared__ float s_y[4][64*17];
    const int cl = blockIdx.x >> 9;
    const int w = __builtin_amdgcn_readfirstlane(threadIdx.x >> 6);
    const int lane = threadIdx.x & 63;            // = d
    const int tile = (blockIdx.x & 511)*4 + w;    // SGPR (uniform)
    const int g = tile & 63, bk = tile >> 6;
    const int k = bk & 3, b = bk >> 2;

    // wave-uniform scalar base pointers -> s_load through constant cache
    const float* Bg = Bsb + (size_t)cl*cs + (size_t)tile*1024;
    const float* Cg = Csb + (size_t)cl*cs + (size_t)tile*1024;
    const float* Dtg = dts_g + (size_t)cl*cs + (size_t)tile*128;

    const int d = lane;
    float A[16];
    {
        const float4* Ab = (const float4*)(A_log + (size_t)(k*64+d)*16);
        #pragma unroll
        for (int qq=0;qq<4;++qq){
            float4 v = Ab[qq];
            A[qq*4+0]=-__expf(v.x)*LOG2E; A[qq*4+1]=-__expf(v.y)*LOG2E;
            A[qq*4+2]=-__expf(v.z)*LOG2E; A[qq*4+3]=-__expf(v.w)*LOG2E;
        }
    }
    float h[16];
    {
        const float4* hb = (const float4*)(hin + (size_t)cl*cs + (size_t)tile*1024 + d*16);
        #pragma unroll
        for (int qq=0;qq<4;++qq){
            float4 v=hb[qq];
            h[qq*4+0]=v.x; h[qq*4+1]=v.y; h[qq*4+2]=v.z; h[qq*4+3]=v.w;
        }
    }
    const float w0 = dt_proj_w[k*128 + d*2], w1 = dt_proj_w[k*128 + d*2 + 1];
    const float bb = dt_proj_b[k*64 + d];
    const float Dv = Dp[k*64 + d];
    const float* up = ((k&1)?xconvT:xconv) + (size_t)cl*cs + (size_t)(b*64+d)*4096;
    float* syw = s_y[w];
    float* obase = outy + (size_t)cl*cs + (size_t)((b*2 + (k&1))*64)*4096;

    for (int t4=0; t4<16; ++t4){
        float u4[4];
        if (k & 2){
            float4 r = *(const float4*)(up + (4092 - g*64 - t4*4));
            u4[0]=r.w; u4[1]=r.z; u4[2]=r.y; u4[3]=r.x;
        } else {
            float4 r = *(const float4*)(up + g*64 + t4*4);
            u4[0]=r.x; u4[1]=r.y; u4[2]=r.z; u4[3]=r.w;
        }
        #pragma unroll
        for (int j=0;j<4;++j){
            const int t = t4*4 + j;
            float2 dtv = *(const float2*)(Dtg + t*2);        // uniform -> s_load
            float dlt = softplus_f(dtv.x*w0 + dtv.y*w1 + bb);
            float du  = dlt * u4[j];
            float y = 0.f;
            #pragma unroll
            for (int qq=0;qq<4;++qq){
                float4 Bv = *(const float4*)(Bg + t*16 + qq*4);   // uniform -> s_load
                float4 Cv = *(const float4*)(Cg + t*16 + qq*4);   // uniform -> s_load
                h[qq*4+0] = h[qq*4+0]*exp2f(dlt*A[qq*4+0]) + du*Bv.x;
                h[qq*4+1] = h[qq*4+1]*exp2f(dlt*A[qq*4+1]) + du*Bv.y;
                h[qq*4+2] = h[qq*4+2]*exp2f(dlt*A[qq*4+2]) + du*Bv.z;
                h[qq*4+3] = h[qq*4+3]*exp2f(dlt*A[qq*4+3]) + du*Bv.w;
                y += h[qq*4+0]*Cv.x + h[qq*4+1]*Cv.y + h[qq*4+2]*Cv.z + h[qq*4+3]*Cv.w;
            }
            syw[d*17 + (t & 15)] = y + Dv*u4[j];
        }
        if ((t4 & 3) == 3){
            const int tb = t4 >> 2;                 // 16-t block index
            if (k & 2){
                const int colr0 = 4095 - g*64 - tb*16;
                #pragma unroll
                for (int qq=0;qq<16;++qq){
                    int i = qq*64 + lane;
                    int dd = i >> 4, jj = i & 15;
                    atomicAdd(&obase[(size_t)dd*4096 + colr0 - jj], syw[dd*17 + jj]);
                }
            } else {
                const int col0 = g*64 + tb*16;
                #pragma unroll
                for (int qq=0;qq<16;++qq){
                    int i = qq*64 + lane;
                    int dd = i >> 4, jj = i & 15;
                    atomicAdd(&obase[(size_t)dd*4096 + col0 + jj], syw[dd*17 + jj]);
                }
            }
        }
    }
}

// ---------------- reduce 2 merged planes -> ysum[b][d][l] ------------------------------
// ysum = m0[l] + T(m1)[l]   (m0 = y0+flip(y2), m1 = y1+flip(y3))
__global__ LB void reduce4_kernel(const float* __restrict__ outy, size_t cs,
                                  float* __restrict__ ysum)
{
    __shared__ float s1[64*65];
    const int cl = blockIdx.x >> 9;
    const int local = blockIdx.x & 511;
    const int b = local >> 6, d = local & 63;
    const int tid = threadIdx.x;
    const float* oy = outy + (size_t)cl*cs;
    const float* m0 = oy + ((size_t)((b*2+0)*64 + d))*4096;
    const float* m1 = oy + ((size_t)((b*2+1)*64 + d))*4096;
    #pragma unroll
    for (int it=0; it<16; ++it){
        int p = tid + it*256;
        s1[(p>>6)*65 + (p&63)] = m1[p];
    }
    __syncthreads();
    float* ys = ysum + (size_t)cl*cs + ((size_t)(b*64 + d))*4096;
    #pragma unroll
    for (int it=0; it<16; ++it){
        int p = tid + it*256;
        int i = p >> 6, j = p & 63;
        ys[p] = m0[p] + s1[j*65 + i];
    }
}

// ---------------- out LN + gate + out_proj + skip + BN + ReLU --------------------------
__global__ LB512 void combine_kernel(const float* __restrict__ ysum, int ch0, size_t cs,
    const float* __restrict__ z, const float* __restrict__ acc,
    const float* __restrict__ onw, const float* __restrict__ onb,
    const float* __restrict__ opw,
    const float* __restrict__ bn_g, const float* __restrict__ bn_b,
    const float* __restrict__ bn_m, const float* __restrict__ bn_v,
    float* __restrict__ out)
{
    __shared__ float s_red[2][8][64];
    __shared__ float s_y[64*65];
    const int cl = blockIdx.x >> 9;
    const int chunk = ch0 + cl;
    const int local = blockIdx.x & 511;
    const int b = local >> 6, lt = local & 63;
    const int l0 = lt*64;
    const int tid = threadIdx.x;
    const int l = tid & 63;
    const int g = __builtin_amdgcn_readfirstlane(tid >> 6);
    const float* ys = ysum + (size_t)cl*cs + (size_t)b*64*4096;
    const int lf = l0 + l;
    float y[8];
    float psum=0.f, psq=0.f;
    #pragma unroll
    for (int i=0;i<8;++i){
        int d = g*8+i;
        float vv = ys[(size_t)d*4096 + lf];
        y[i]=vv; psum+=vv; psq+=vv*vv;
    }
    s_red[0][g][l]=psum; s_red[1][g][l]=psq;
    __syncthreads();
    float mu=0.f, vsum=0.f;
    #pragma unroll
    for (int gg=0;gg<8;++gg){ mu += s_red[0][gg][l]; vsum += s_red[1][gg][l]; }
    mu *= (1.f/64.f);
    float var = vsum*(1.f/64.f) - mu*mu;
    float rs = rsqrtf(var + 1e-5f);
    const float* zp = z + (size_t)cl*cs + (size_t)b*64*4096 + lf;
    #pragma unroll
    for (int i=0;i<8;++i){
        int d = g*8+i;
        float t2 = (y[i]-mu)*rs*onw[d] + onb[d];
        float zv = zp[(size_t)d*4096];
        s_y[l*65 + d] = t2 * silu_f(zv);
    }
    __syncthreads();
    float a4[4] = {0.f,0.f,0.f,0.f};
    for (int d=0; d<64; ++d){
        float xval = s_y[l*65+d];
        #pragma unroll
        for (int j=0;j<4;++j) a4[j] += opw[(g*4+j)*64+d]*xval;   // uniform -> scalar loads
    }
    const float* ap = acc + (size_t)chunk*1048576 + (size_t)b*32*4096 + lf;
    #pragma unroll
    for (int j=0;j<4;++j){
        int c = g*4+j, ch = chunk*32 + c;
        float s = a4[j] + ap[(size_t)c*4096];
        float bnv = (s - bn_m[ch])*rsqrtf(bn_v[ch]+1e-5f)*bn_g[ch] + bn_b[ch];
        out[((size_t)b*128+ch)*4096 + lf] = fmaxf(bnv, 0.f);
    }
}

extern "C" void kernel_launch(void* const* d_in, const int* in_sizes, int n_in,
                              void* d_out, int out_size, void* d_ws, size_t ws_size,
                              hipStream_t stream) {
    const float* x         = (const float*)d_in[0];
    const float* ln_w      = (const float*)d_in[19];
    const float* ln_b      = (const float*)d_in[20];
    const float* in_proj_w = (const float*)d_in[21];
    const float* conv_w    = (const float*)d_in[22];
    const float* conv_b    = (const float*)d_in[23];
    const float* x_proj_w  = (const float*)d_in[24];
    const float* dt_proj_w = (const float*)d_in[25];
    const float* dt_proj_b = (const float*)d_in[26];
    const float* A_log     = (const float*)d_in[27];
    const float* Dp        = (const float*)d_in[28];
    const float* onw       = (const float*)d_in[29];
    const float* onb       = (const float*)d_in[30];
    const float* opw       = (const float*)d_in[31];
    const float* bn_g      = (const float*)d_in[32];
    const float* bn_b      = (const float*)d_in[33];
    const float* bn_m      = (const float*)d_in[34];
    const float* bn_v      = (const float*)d_in[35];
    float* out = (float*)d_out;

    // per-chunk pool layout (floats), liveness-safe aliasing:
    //  outy (2 merged planes, 4.19M) overlays xc [0..2.1M) + hlo [2.1..4.19M)
    //  ysum aliases xconv (dead after scan3)
    const size_t F_OUTY = 0;          // 4,194,304 floats: [b][2][64][4096]
    const size_t F_XC   = 0;
    const size_t F_HLO  = 2097152;
    const size_t F_Z    = 4194304;
    const size_t F_XCV  = 6291456;    // ysum alias
    const size_t F_XCVT = 8388608;
    const size_t F_BSB  = 10485760;
    const size_t F_CSB  = 12582912;
    const size_t F_DTS  = 14680064;
    const size_t F_SSUM = 14942208;
    const size_t F_HIN  = 15073280;
    const size_t CSF    = 17170432;   // floats per chunk pool (68.7 MB)

    float* ws = (float*)d_ws;
    float* acc  = ws;                 // 3 x 1,048,576 floats
    float* pool = acc + 3145728;

    const size_t ws_f = ws_size / sizeof(float);
    int nch_max = 1;
    if (ws_f >= 3145728 + 3*CSF) nch_max = 3;
    else if (ws_f >= 3145728 + 2*CSF) nch_max = 2;

    float* xc     = pool + F_XC;
    float* z      = pool + F_Z;
    float* xconv  = pool + F_XCV;
    float* xconvT = pool + F_XCVT;
    float* Bsb    = pool + F_BSB;
    float* Csb    = pool + F_CSB;
    float* dts_g  = pool + F_DTS;
    float* Ssum   = pool + F_SSUM;
    float* hlo    = pool + F_HLO;
    float* hin    = pool + F_HIN;
    float* outy   = pool + F_OUTY;
    float* ysum   = pool + F_XCV;

    // axial (3 chunks) + chunk-4 BN/ReLU passthrough, single launch
    AxialArgs aargs;
    for (int chunk=0; chunk<3; ++chunk)
        for (int jj=0; jj<6; ++jj)
            aargs.w[chunk*6+jj] = (const float*)d_in[1 + chunk*6 + jj];
    axial_kernel<<<768+1024, 256, 0, stream>>>(x, aargs, acc, bn_g, bn_b, bn_m, bn_v, out);

    int done = 0;
    while (done < 3){
        const int nch = (3 - done < nch_max) ? (3 - done) : nch_max;
        const size_t cs = (nch > 1) ? CSF : 0;
        const int ch0 = done;

        lnproj_kernel<<<nch*512, 512, 0, stream>>>(acc, ch0, cs, ln_w, ln_b, in_proj_w, xc, z);
        conv3_kernel<<<nch*512, 256, 0, stream>>>(xc, cs, conv_w, conv_b, xconv, xconvT);
        projscan1_kernel<<<nch*2048, 256, 0, stream>>>(xconv, xconvT, cs,
                                                       x_proj_w, dt_proj_w, dt_proj_b,
                                                       A_log, Bsb, Csb, dts_g, Ssum, hlo);
        scan2_kernel<<<nch*512, 64, 0, stream>>>(Ssum, cs, hlo, A_log, hin);
        // zero the merged outy planes (xc/hlo dead by now), then atomic-accumulate scan3
        for (int cl2=0; cl2<nch; ++cl2)
            hipMemsetAsync(outy + (size_t)cl2*cs, 0, (size_t)4194304*sizeof(float), stream);
        scan3_kernel<<<nch*512, 256, 0, stream>>>(xconv, xconvT, cs, Bsb, Csb, dts_g,
                                                  dt_proj_w, dt_proj_b, A_log, Dp, hin, outy);
        reduce4_kernel<<<nch*512, 256, 0, stream>>>(outy, cs, ysum);
        combine_kernel<<<nch*512, 512, 0, stream>>>(ysum, ch0, cs, z, acc, onw, onb, opw,
                                                    bn_g, bn_b, bn_m, bn_v, out);
        done += nch;
    }
}

// Round 17
// 423.777 us; speedup vs baseline: 1.3480x; 1.3480x over previous
//
#include <hip/hip_runtime.h>
#include <math.h>

#define LB __launch_bounds__(256)
#define LB512 __launch_bounds__(512)
#define LB64 __launch_bounds__(64)

// B=8, DIM=128, C=32, DI=64, H=W=64, L=4096, K=4, N=16, R=2, G=64 chunks of 64
#define LOG2E 1.44269504088896340736f
static __device__ __forceinline__ float silu_f(float x){ return x / (1.f + __expf(-x)); }
static __device__ __forceinline__ float softplus_f(float x){
    return (x > 20.f) ? x : __logf(1.f + __expf(x));
}

struct AxialArgs { const float* w[18]; };

// ---------------- axial depthwise (3 chunks) + fused chunk-4 BN/ReLU passthrough -------
__global__ LB void axial_kernel(const float* __restrict__ x, AxialArgs args,
    float* __restrict__ acc,
    const float* __restrict__ bn_g, const float* __restrict__ bn_b,
    const float* __restrict__ bn_m, const float* __restrict__ bn_v,
    float* __restrict__ out)
{
    __shared__ float s0[4096];
    __shared__ float s1[4096];
    if (blockIdx.x >= 768){
        const int gid = (blockIdx.x - 768)*256 + threadIdx.x;
        const int e = gid*4;
        const int l = e & 4095, bc = e >> 12;
        const int c = bc & 31, b = bc >> 5;
        const int ch = 96 + c;
        const size_t idx = ((size_t)b*128+ch)*4096 + l;
        float4 v = *(const float4*)&x[idx];
        const float sc = rsqrtf(bn_v[ch]+1e-5f)*bn_g[ch];
        const float mb = bn_m[ch], bbv = bn_b[ch];
        v.x = fmaxf((v.x-mb)*sc+bbv, 0.f);
        v.y = fmaxf((v.y-mb)*sc+bbv, 0.f);
        v.z = fmaxf((v.z-mb)*sc+bbv, 0.f);
        v.w = fmaxf((v.w-mb)*sc+bbv, 0.f);
        *(float4*)&out[idx] = v;
        return;
    }
    const int chunk = blockIdx.x >> 8;
    const int bc = blockIdx.x & 255;      // b*32 + c
    const int b = bc >> 5, c = bc & 31;
    const int dil = chunk + 1;
    const float* mh_w = args.w[chunk*6+0];
    const float* mh_b = args.w[chunk*6+1];
    const float* mw_w = args.w[chunk*6+2];
    const float* mw_b = args.w[chunk*6+3];
    const float* cw   = args.w[chunk*6+4];
    const float* cb   = args.w[chunk*6+5];
    const int tid = threadIdx.x;
    const float* xin = x + ((size_t)(b*128 + chunk*32 + c)) * 4096;
    float orig[16];
    #pragma unroll
    for (int kk=0;kk<16;++kk){ float v=xin[tid+kk*256]; orig[kk]=v; s0[tid+kk*256]=v; }
    __syncthreads();

    float w7[7];
    #pragma unroll
    for (int t=0;t<7;++t) w7[t]=mw_w[c*7+t];
    float bias = mw_b[c];
    float v[16];
    #pragma unroll
    for (int kk=0;kk<16;++kk){
        int p=tid+kk*256, i=p>>6, j=p&63;
        float s=bias;
        #pragma unroll
        for (int t=0;t<7;++t){ int jj=j+(t-3)*dil; if (jj>=0&&jj<64) s+=s0[i*64+jj]*w7[t]; }
        v[kk]=s;
    }
    #pragma unroll
    for (int kk=0;kk<16;++kk) s1[tid+kk*256]=v[kk];
    __syncthreads();

    #pragma unroll
    for (int t=0;t<7;++t) w7[t]=mh_w[c*7+t];
    bias = mh_b[c];
    #pragma unroll
    for (int kk=0;kk<16;++kk){
        int p=tid+kk*256, i=p>>6, j=p&63;
        float s=bias;
        #pragma unroll
        for (int t=0;t<7;++t){ int ii=i+(t-3)*dil; if (ii>=0&&ii<64) s+=s1[ii*64+j]*w7[t]; }
        v[kk]=s;
    }
    __syncthreads();
    #pragma unroll
    for (int kk=0;kk<16;++kk) s0[tid+kk*256]=v[kk];
    __syncthreads();

    float w9[9];
    #pragma unroll
    for (int t=0;t<9;++t) w9[t]=cw[c*9+t];
    bias = cb[c];
    float* aout = acc + (size_t)chunk*1048576 + ((size_t)(b*32+c))*4096;
    #pragma unroll
    for (int kk=0;kk<16;++kk){
        int p=tid+kk*256, i=p>>6, j=p&63;
        float s=bias;
        #pragma unroll
        for (int a=0;a<3;++a){
            int ii=i+(a-1)*dil; if (ii<0||ii>=64) continue;
            #pragma unroll
            for (int bb2=0;bb2<3;++bb2){
                int jj=j+(bb2-1)*dil; if (jj<0||jj>=64) continue;
                s += s0[ii*64+jj]*w9[a*3+bb2];
            }
        }
        aout[p] = s + orig[kk];
    }
}

// ---------------- LN(C=32) + in_proj (32 -> 128), split xc / z -------------------------
__global__ LB512 void lnproj_kernel(const float* __restrict__ acc, int ch0, size_t cs,
    const float* __restrict__ ln_w, const float* __restrict__ ln_b,
    const float* __restrict__ in_proj_w,
    float* __restrict__ xc, float* __restrict__ z)
{
    __shared__ float s_a[32*65];
    const int cl = blockIdx.x >> 9;
    const int local = blockIdx.x & 511;
    const int chunk = ch0 + cl;
    const int b = local >> 6, lt = local & 63;
    const int l0 = lt*64;
    const int tid = threadIdx.x;
    const float* ab = acc + (size_t)chunk*1048576 + (size_t)b*32*4096 + l0;
    for (int i=tid;i<2048;i+=512){ int c=i>>6, j=i&63; s_a[c*65+j]=ab[(size_t)c*4096 + j]; }
    __syncthreads();
    const int l = tid & 63;
    const int g = __builtin_amdgcn_readfirstlane(tid >> 6);
    float v[32];
    float mu=0.f;
    #pragma unroll
    for (int c=0;c<32;++c){ v[c]=s_a[c*65+l]; mu+=v[c]; }
    mu *= (1.f/32.f);
    float var=0.f;
    #pragma unroll
    for (int c=0;c<32;++c){ float d2=v[c]-mu; var+=d2*d2; }
    var *= (1.f/32.f);
    float rs = rsqrtf(var+1e-5f);
    #pragma unroll
    for (int c=0;c<32;++c) v[c] = (v[c]-mu)*rs*ln_w[c] + ln_b[c];
    float* xcp = xc + (size_t)cl*cs + (size_t)b*64*4096 + l0 + l;
    float* zp  = z  + (size_t)cl*cs + (size_t)b*64*4096 + l0 + l;
    for (int e=g*16; e<g*16+16; ++e){
        const float* wr = in_proj_w + e*32;   // uniform rows -> scalar loads
        float s=0.f;
        #pragma unroll
        for (int c=0;c<32;++c) s += wr[c]*v[c];
        if (e<64) xcp[(size_t)e*4096]=s; else zp[(size_t)(e-64)*4096]=s;
    }
}

// ---------------- 3x3 dwconv (dil=1) + SiLU, fused transpose output --------------------
__global__ LB void conv3_kernel(const float* __restrict__ xc, size_t cs,
    const float* __restrict__ conv_w, const float* __restrict__ conv_b,
    float* __restrict__ xconv, float* __restrict__ xconvT)
{
    __shared__ float s0[4096];
    __shared__ float s1[64*65];
    const int cl = blockIdx.x >> 9;
    const int bd = blockIdx.x & 511;  // b*64 + d
    const int d = bd & 63;
    const int tid = threadIdx.x;
    const float* in = xc + (size_t)cl*cs + (size_t)bd*4096;
    #pragma unroll
    for (int kk=0;kk<16;++kk) s0[tid+kk*256]=in[tid+kk*256];
    __syncthreads();
    float w9[9];
    #pragma unroll
    for (int t=0;t<9;++t) w9[t]=conv_w[d*9+t];
    float bias = conv_b[d];
    float* outp = xconv + (size_t)cl*cs + (size_t)bd*4096;
    #pragma unroll
    for (int kk=0;kk<16;++kk){
        int p=tid+kk*256, i=p>>6, j=p&63;
        float s=bias;
        #pragma unroll
        for (int a=0;a<3;++a){
            int ii=i+a-1; if (ii<0||ii>=64) continue;
            #pragma unroll
            for (int bb2=0;bb2<3;++bb2){
                int jj=j+bb2-1; if (jj<0||jj>=64) continue;
                s += s0[ii*64+jj]*w9[a*3+bb2];
            }
        }
        s = silu_f(s);
        outp[p]=s;
        s1[i*65+j]=s;
    }
    __syncthreads();
    float* outT = xconvT + (size_t)cl*cs + (size_t)bd*4096;
    #pragma unroll
    for (int kk=0;kk<16;++kk){ int p=tid+kk*256; outT[p] = s1[(p&63)*65 + (p>>6)]; }
}

// ---------------- fused x_proj + dt_proj + softplus + scan phase 1 ---------------------
// grid nch*2048 (1 tile/block); GEMM scatters into PADDED temps (conflict-free);
// shared dlt pass (softplus once per (t,d)); scan: lane=d, wave w owns n-quad w
__global__ LB void projscan1_kernel(const float* __restrict__ xconv, const float* __restrict__ xconvT,
    size_t cs,
    const float* __restrict__ x_proj_w, const float* __restrict__ dt_proj_w,
    const float* __restrict__ dt_proj_b, const float* __restrict__ A_log,
    float* __restrict__ Bsb, float* __restrict__ Csb, float* __restrict__ dts_g,
    float* __restrict__ Ssum, float* __restrict__ hloc)
{
    __shared__ float s_x[64*65];                  // [t][d] u; overwritten with du
    __shared__ float s_dlt[64*65];                // scratch Bp/Cp; later dlt [t][d]
    __shared__ __align__(16) float s_B[1024];     // packed [t][16] for scan broadcast
    __shared__ __align__(8) float s_dts[128];     // [t][2]
    float* s_Bp = s_dlt;                          // padded [t][17]
    float* s_Cp = s_dlt + 1152;                   // padded [t][17]
    const int cl = blockIdx.x >> 11;
    const int blkL = blockIdx.x & 2047;
    const int g = blkL & 63, bk = blkL >> 6;
    const int k = bk & 3, b = bk >> 2;
    const int tid = threadIdx.x;
    const int t0 = g*64;
    const float* src = ((k & 1) ? xconvT : xconv) + (size_t)cl*cs;
    const float* sb = src + (size_t)b*64*4096;
    // float4 staging: 4 rows x 256B per wave-instruction
    #pragma unroll
    for (int it=0; it<4; ++it){
        const int i4 = tid + it*256;           // 0..1023
        const int d = i4 >> 4, jq = (i4 & 15)*4;
        if (k & 2){
            float4 r = *(const float4*)(sb + (size_t)d*4096 + (4092 - t0 - jq));
            s_x[(jq+3)*65 + d] = r.x;
            s_x[(jq+2)*65 + d] = r.y;
            s_x[(jq+1)*65 + d] = r.z;
            s_x[(jq+0)*65 + d] = r.w;
        } else {
            float4 r = *(const float4*)(sb + (size_t)d*4096 + t0 + jq);
            s_x[(jq+0)*65 + d] = r.x;
            s_x[(jq+1)*65 + d] = r.y;
            s_x[(jq+2)*65 + d] = r.z;
            s_x[(jq+3)*65 + d] = r.w;
        }
    }
    __syncthreads();

    // ---- proj GEMM: q-group owns 9 (or 7) rows of x_proj_w; padded scatter ----
    {
        const int t = tid & 63;
        const int q = __builtin_amdgcn_readfirstlane(tid >> 6);
        const float* wp = x_proj_w + k*2176;
        float acc9[9];
        #pragma unroll
        for (int r=0;r<9;++r) acc9[r]=0.f;
        const int r0 = q*9;
        const int nr = (q==3)?7:9;
        for (int ch=0; ch<4; ++ch){
            float xv[16];
            #pragma unroll
            for (int i=0;i<16;++i) xv[i] = s_x[t*65 + ch*16 + i];
            #pragma unroll
            for (int r=0;r<9;++r){
                if (r < nr){
                    const float* wr = wp + (r0+r)*64 + ch*16;   // uniform -> scalar loads
                    float s=0.f;
                    #pragma unroll
                    for (int i=0;i<16;++i) s += wr[i]*xv[i];
                    acc9[r] += s;
                }
            }
        }
        #pragma unroll
        for (int r=0;r<9;++r){
            if (r<nr){
                int row = r0 + r;
                if (row < 2)       s_dts[t*2 + row]       = acc9[r];
                else if (row < 18) s_Bp[t*17 + (row-2)]   = acc9[r];
                else               s_Cp[t*17 + (row-18)]  = acc9[r];
            }
        }
    }
    __syncthreads();

    // ---- flush B/C/dts (coalesced, packed) + repack B for scan broadcast ----
    {
        float* BsbC = Bsb + (size_t)cl*cs;
        float* CsbC = Csb + (size_t)cl*cs;
        const size_t tb = (size_t)blkL*1024;
        for (int i=tid;i<1024;i+=256){
            int a = (i>>4)*17 + (i&15);
            float bv = s_Bp[a], cv = s_Cp[a];
            BsbC[tb+i]=bv; CsbC[tb+i]=cv;
            s_B[i]=bv;
        }
        if (tid<128) (dts_g + (size_t)cl*cs)[(size_t)blkL*128 + tid] = s_dts[tid];
    }
    __syncthreads();   // Bp/Cp reads done before dlt overwrite

    // ---- shared dlt pass: softplus once per (t,d); du in place ----
    {
        const int d_ = tid & 63, part = tid >> 6;
        const float w0 = dt_proj_w[k*128 + d_*2], w1 = dt_proj_w[k*128 + d_*2 + 1];
        const float bb = dt_proj_b[k*64 + d_];
        #pragma unroll
        for (int i=0;i<16;++i){
            const int t = part*16 + i;
            float dlt = softplus_f(s_dts[t*2]*w0 + s_dts[t*2+1]*w1 + bb);
            s_dlt[t*65 + d_] = dlt;
            s_x[t*65 + d_] *= dlt;        // du
        }
    }
    __syncthreads();

    // ---- local scan: lane = d, wave w owns n-quad w; B as b128 broadcast ----
    const int d = tid & 63;
    const int w = __builtin_amdgcn_readfirstlane(tid >> 6);
    float4 Av = *(const float4*)(A_log + ((size_t)(k*64+d)*16 + w*4));
    const float A0 = -__expf(Av.x)*LOG2E, A1 = -__expf(Av.y)*LOG2E,
                A2 = -__expf(Av.z)*LOG2E, A3 = -__expf(Av.w)*LOG2E;
    float h0=0,h1=0,h2=0,h3=0, S=0.f;
    #pragma unroll 4
    for (int t=0;t<64;++t){
        float dlt = s_dlt[t*65+d];
        float du  = s_x[t*65+d];
        S += dlt;
        float4 Bv = *(const float4*)&s_B[t*16 + w*4];   // uniform addr -> broadcast
        h0 = h0*exp2f(dlt*A0) + du*Bv.x;
        h1 = h1*exp2f(dlt*A1) + du*Bv.y;
        h2 = h2*exp2f(dlt*A2) + du*Bv.z;
        h3 = h3*exp2f(dlt*A3) + du*Bv.w;
    }
    if (w == 0) (Ssum + (size_t)cl*cs)[(size_t)blkL*64 + d] = S;
    ((float4*)(hloc + (size_t)cl*cs))[(size_t)blkL*256 + d*4 + w] = make_float4(h0,h1,h2,h3);
}

// ---------------- scan phase 2: chunk combine; Aprod = exp2(A * S_chunk) ---------------
// grid nch*512 x 64 thr (1 wave / block, all CUs covered)
__global__ LB64 void scan2_kernel(const float* __restrict__ Ssum, size_t cs,
    const float* __restrict__ hloc, const float* __restrict__ A_log,
    float* __restrict__ hin)
{
    const int cl = blockIdx.x >> 9;
    const int j = (blockIdx.x & 511)*64 + threadIdx.x;   // 0..32767 : (b,k,dn)
    const int bk = j >> 10, dn = j & 1023;
    const int k = bk & 3, d = dn >> 4, n = dn & 15;
    const float* SsC = Ssum + (size_t)cl*cs;
    const float* hlC = hloc + (size_t)cl*cs;
    float* hinC = hin + (size_t)cl*cs;
    const float A = -__expf(A_log[(size_t)(k*64+d)*16 + n]) * LOG2E;
    float h = 0.f;
    #pragma unroll 4
    for (int g=0; g<64; ++g){
        const size_t o = ((size_t)bk*64 + g)*1024 + dn;
        hinC[o] = h;
        float S = SsC[((size_t)bk*64 + g)*64 + d];
        h = exp2f(A*S)*h + hlC[o];
    }
}

// ---------------- scan phase 3: 1 wave per tile; B/C/dts via SCALAR loads --------------
// y staged in s_y, flushed coalesced; flipped dirs (k>=2) atomicAdd into fwd planes
// outy layout: [cl][b][plane=k&1][64 d][4096]  (memset to 0 before launch)
__global__ LB void scan3_kernel(const float* __restrict__ xconv, const float* __restrict__ xconvT,
    size_t cs,
    const float* __restrict__ Bsb, const float* __restrict__ Csb,
    const float* __restrict__ dts_g,
    const float* __restrict__ dt_proj_w, const float* __restrict__ dt_proj_b,
    const float* __restrict__ A_log, const float* __restrict__ Dp,
    const float* __restrict__ hin, float* __restrict__ outy)
{
    __shared__ float s_y[4][64*17];
    const int cl = blockIdx.x >> 9;
    const int w = __builtin_amdgcn_readfirstlane(threadIdx.x >> 6);
    const int lane = threadIdx.x & 63;            // = d
    const int tile = (blockIdx.x & 511)*4 + w;    // SGPR (uniform)
    const int g = tile & 63, bk = tile >> 6;
    const int k = bk & 3, b = bk >> 2;

    // wave-uniform scalar base pointers -> s_load through constant cache
    const float* Bg = Bsb + (size_t)cl*cs + (size_t)tile*1024;
    const float* Cg = Csb + (size_t)cl*cs + (size_t)tile*1024;
    const float* Dtg = dts_g + (size_t)cl*cs + (size_t)tile*128;

    const int d = lane;
    float A[16];
    {
        const float4* Ab = (const float4*)(A_log + (size_t)(k*64+d)*16);
        #pragma unroll
        for (int qq=0;qq<4;++qq){
            float4 v = Ab[qq];
            A[qq*4+0]=-__expf(v.x)*LOG2E; A[qq*4+1]=-__expf(v.y)*LOG2E;
            A[qq*4+2]=-__expf(v.z)*LOG2E; A[qq*4+3]=-__expf(v.w)*LOG2E;
        }
    }
    float h[16];
    {
        const float4* hb = (const float4*)(hin + (size_t)cl*cs + (size_t)tile*1024 + d*16);
        #pragma unroll
        for (int qq=0;qq<4;++qq){
            float4 v=hb[qq];
            h[qq*4+0]=v.x; h[qq*4+1]=v.y; h[qq*4+2]=v.z; h[qq*4+3]=v.w;
        }
    }
    const float w0 = dt_proj_w[k*128 + d*2], w1 = dt_proj_w[k*128 + d*2 + 1];
    const float bb = dt_proj_b[k*64 + d];
    const float Dv = Dp[k*64 + d];
    const float* up = ((k&1)?xconvT:xconv) + (size_t)cl*cs + (size_t)(b*64+d)*4096;
    float* syw = s_y[w];
    float* obase = outy + (size_t)cl*cs + (size_t)((b*2 + (k&1))*64)*4096;

    for (int t4=0; t4<16; ++t4){
        float u4[4];
        if (k & 2){
            float4 r = *(const float4*)(up + (4092 - g*64 - t4*4));
            u4[0]=r.w; u4[1]=r.z; u4[2]=r.y; u4[3]=r.x;
        } else {
            float4 r = *(const float4*)(up + g*64 + t4*4);
            u4[0]=r.x; u4[1]=r.y; u4[2]=r.z; u4[3]=r.w;
        }
        #pragma unroll
        for (int j=0;j<4;++j){
            const int t = t4*4 + j;
            float2 dtv = *(const float2*)(Dtg + t*2);        // uniform -> s_load
            float dlt = softplus_f(dtv.x*w0 + dtv.y*w1 + bb);
            float du  = dlt * u4[j];
            float y = 0.f;
            #pragma unroll
            for (int qq=0;qq<4;++qq){
                float4 Bv = *(const float4*)(Bg + t*16 + qq*4);   // uniform -> s_load
                float4 Cv = *(const float4*)(Cg + t*16 + qq*4);   // uniform -> s_load
                h[qq*4+0] = h[qq*4+0]*exp2f(dlt*A[qq*4+0]) + du*Bv.x;
                h[qq*4+1] = h[qq*4+1]*exp2f(dlt*A[qq*4+1]) + du*Bv.y;
                h[qq*4+2] = h[qq*4+2]*exp2f(dlt*A[qq*4+2]) + du*Bv.z;
                h[qq*4+3] = h[qq*4+3]*exp2f(dlt*A[qq*4+3]) + du*Bv.w;
                y += h[qq*4+0]*Cv.x + h[qq*4+1]*Cv.y + h[qq*4+2]*Cv.z + h[qq*4+3]*Cv.w;
            }
            syw[d*17 + (t & 15)] = y + Dv*u4[j];
        }
        if ((t4 & 3) == 3){
            const int tb = t4 >> 2;                 // 16-t block index
            if (k & 2){
                const int colr0 = 4095 - g*64 - tb*16;
                #pragma unroll
                for (int qq=0;qq<16;++qq){
                    int i = qq*64 + lane;
                    int dd = i >> 4, jj = i & 15;
                    atomicAdd(&obase[(size_t)dd*4096 + colr0 - jj], syw[dd*17 + jj]);
                }
            } else {
                const int col0 = g*64 + tb*16;
                #pragma unroll
                for (int qq=0;qq<16;++qq){
                    int i = qq*64 + lane;
                    int dd = i >> 4, jj = i & 15;
                    atomicAdd(&obase[(size_t)dd*4096 + col0 + jj], syw[dd*17 + jj]);
                }
            }
        }
    }
}

// ---------------- reduce 2 merged planes -> ysum[b][d][l] ------------------------------
// ysum = m0[l] + T(m1)[l]   (m0 = y0+flip(y2), m1 = y1+flip(y3))
__global__ LB void reduce4_kernel(const float* __restrict__ outy, size_t cs,
                                  float* __restrict__ ysum)
{
    __shared__ float s1[64*65];
    const int cl = blockIdx.x >> 9;
    const int local = blockIdx.x & 511;
    const int b = local >> 6, d = local & 63;
    const int tid = threadIdx.x;
    const float* oy = outy + (size_t)cl*cs;
    const float* m0 = oy + ((size_t)((b*2+0)*64 + d))*4096;
    const float* m1 = oy + ((size_t)((b*2+1)*64 + d))*4096;
    #pragma unroll
    for (int it=0; it<16; ++it){
        int p = tid + it*256;
        s1[(p>>6)*65 + (p&63)] = m1[p];
    }
    __syncthreads();
    float* ys = ysum + (size_t)cl*cs + ((size_t)(b*64 + d))*4096;
    #pragma unroll
    for (int it=0; it<16; ++it){
        int p = tid + it*256;
        int i = p >> 6, j = p & 63;
        ys[p] = m0[p] + s1[j*65 + i];
    }
}

// ---------------- out LN + gate + out_proj + skip + BN + ReLU --------------------------
__global__ LB512 void combine_kernel(const float* __restrict__ ysum, int ch0, size_t cs,
    const float* __restrict__ z, const float* __restrict__ acc,
    const float* __restrict__ onw, const float* __restrict__ onb,
    const float* __restrict__ opw,
    const float* __restrict__ bn_g, const float* __restrict__ bn_b,
    const float* __restrict__ bn_m, const float* __restrict__ bn_v,
    float* __restrict__ out)
{
    __shared__ float s_red[2][8][64];
    __shared__ float s_y[64*65];
    const int cl = blockIdx.x >> 9;
    const int chunk = ch0 + cl;
    const int local = blockIdx.x & 511;
    const int b = local >> 6, lt = local & 63;
    const int l0 = lt*64;
    const int tid = threadIdx.x;
    const int l = tid & 63;
    const int g = __builtin_amdgcn_readfirstlane(tid >> 6);
    const float* ys = ysum + (size_t)cl*cs + (size_t)b*64*4096;
    const int lf = l0 + l;
    float y[8];
    float psum=0.f, psq=0.f;
    #pragma unroll
    for (int i=0;i<8;++i){
        int d = g*8+i;
        float vv = ys[(size_t)d*4096 + lf];
        y[i]=vv; psum+=vv; psq+=vv*vv;
    }
    s_red[0][g][l]=psum; s_red[1][g][l]=psq;
    __syncthreads();
    float mu=0.f, vsum=0.f;
    #pragma unroll
    for (int gg=0;gg<8;++gg){ mu += s_red[0][gg][l]; vsum += s_red[1][gg][l]; }
    mu *= (1.f/64.f);
    float var = vsum*(1.f/64.f) - mu*mu;
    float rs = rsqrtf(var + 1e-5f);
    const float* zp = z + (size_t)cl*cs + (size_t)b*64*4096 + lf;
    #pragma unroll
    for (int i=0;i<8;++i){
        int d = g*8+i;
        float t2 = (y[i]-mu)*rs*onw[d] + onb[d];
        float zv = zp[(size_t)d*4096];
        s_y[l*65 + d] = t2 * silu_f(zv);
    }
    __syncthreads();
    float a4[4] = {0.f,0.f,0.f,0.f};
    for (int d=0; d<64; ++d){
        float xval = s_y[l*65+d];
        #pragma unroll
        for (int j=0;j<4;++j) a4[j] += opw[(g*4+j)*64+d]*xval;   // uniform -> scalar loads
    }
    const float* ap = acc + (size_t)chunk*1048576 + (size_t)b*32*4096 + lf;
    #pragma unroll
    for (int j=0;j<4;++j){
        int c = g*4+j, ch = chunk*32 + c;
        float s = a4[j] + ap[(size_t)c*4096];
        float bnv = (s - bn_m[ch])*rsqrtf(bn_v[ch]+1e-5f)*bn_g[ch] + bn_b[ch];
        out[((size_t)b*128+ch)*4096 + lf] = fmaxf(bnv, 0.f);
    }
}

extern "C" void kernel_launch(void* const* d_in, const int* in_sizes, int n_in,
                              void* d_out, int out_size, void* d_ws, size_t ws_size,
                              hipStream_t stream) {
    const float* x         = (const float*)d_in[0];
    const float* ln_w      = (const float*)d_in[19];
    const float* ln_b      = (const float*)d_in[20];
    const float* in_proj_w = (const float*)d_in[21];
    const float* conv_w    = (const float*)d_in[22];
    const float* conv_b    = (const float*)d_in[23];
    const float* x_proj_w  = (const float*)d_in[24];
    const float* dt_proj_w = (const float*)d_in[25];
    const float* dt_proj_b = (const float*)d_in[26];
    const float* A_log     = (const float*)d_in[27];
    const float* Dp        = (const float*)d_in[28];
    const float* onw       = (const float*)d_in[29];
    const float* onb       = (const float*)d_in[30];
    const float* opw       = (const float*)d_in[31];
    const float* bn_g      = (const float*)d_in[32];
    const float* bn_b      = (const float*)d_in[33];
    const float* bn_m      = (const float*)d_in[34];
    const float* bn_v      = (const float*)d_in[35];
    float* out = (float*)d_out;

    // per-chunk pool layout (floats), liveness-safe aliasing:
    //  outy (2 merged planes, 4.19M) overlays xc [0..2.1M) + hlo [2.1..4.19M)
    //  ysum aliases xconv (dead after scan3)
    const size_t F_OUTY = 0;          // 4,194,304 floats: [b][2][64][4096]
    const size_t F_XC   = 0;
    const size_t F_HLO  = 2097152;
    const size_t F_Z    = 4194304;
    const size_t F_XCV  = 6291456;    // ysum alias
    const size_t F_XCVT = 8388608;
    const size_t F_BSB  = 10485760;
    const size_t F_CSB  = 12582912;
    const size_t F_DTS  = 14680064;
    const size_t F_SSUM = 14942208;
    const size_t F_HIN  = 15073280;
    const size_t CSF    = 17170432;   // floats per chunk pool (68.7 MB)

    float* ws = (float*)d_ws;
    float* acc  = ws;                 // 3 x 1,048,576 floats
    float* pool = acc + 3145728;

    const size_t ws_f = ws_size / sizeof(float);
    int nch_max = 1;
    if (ws_f >= 3145728 + 3*CSF) nch_max = 3;
    else if (ws_f >= 3145728 + 2*CSF) nch_max = 2;

    float* xc     = pool + F_XC;
    float* z      = pool + F_Z;
    float* xconv  = pool + F_XCV;
    float* xconvT = pool + F_XCVT;
    float* Bsb    = pool + F_BSB;
    float* Csb    = pool + F_CSB;
    float* dts_g  = pool + F_DTS;
    float* Ssum   = pool + F_SSUM;
    float* hlo    = pool + F_HLO;
    float* hin    = pool + F_HIN;
    float* outy   = pool + F_OUTY;
    float* ysum   = pool + F_XCV;

    // axial (3 chunks) + chunk-4 BN/ReLU passthrough, single launch
    AxialArgs aargs;
    for (int chunk=0; chunk<3; ++chunk)
        for (int jj=0; jj<6; ++jj)
            aargs.w[chunk*6+jj] = (const float*)d_in[1 + chunk*6 + jj];
    axial_kernel<<<768+1024, 256, 0, stream>>>(x, aargs, acc, bn_g, bn_b, bn_m, bn_v, out);

    int done = 0;
    while (done < 3){
        const int nch = (3 - done < nch_max) ? (3 - done) : nch_max;
        const size_t cs = (nch > 1) ? CSF : 0;
        const int ch0 = done;

        lnproj_kernel<<<nch*512, 512, 0, stream>>>(acc, ch0, cs, ln_w, ln_b, in_proj_w, xc, z);
        conv3_kernel<<<nch*512, 256, 0, stream>>>(xc, cs, conv_w, conv_b, xconv, xconvT);
        projscan1_kernel<<<nch*2048, 256, 0, stream>>>(xconv, xconvT, cs,
                                                       x_proj_w, dt_proj_w, dt_proj_b,
                                                       A_log, Bsb, Csb, dts_g, Ssum, hlo);
        scan2_kernel<<<nch*512, 64, 0, stream>>>(Ssum, cs, hlo, A_log, hin);
        // zero the merged outy planes (xc/hlo dead by now), then atomic-accumulate scan3
        for (int cl2=0; cl2<nch; ++cl2)
            hipMemsetAsync(outy + (size_t)cl2*cs, 0, (size_t)4194304*sizeof(float), stream);
        scan3_kernel<<<nch*512, 256, 0, stream>>>(xconv, xconvT, cs, Bsb, Csb, dts_g,
                                                  dt_proj_w, dt_proj_b, A_log, Dp, hin, outy);
        reduce4_kernel<<<nch*512, 256, 0, stream>>>(outy, cs, ysum);
        combine_kernel<<<nch*512, 512, 0, stream>>>(ysum, ch0, cs, z, acc, onw, onb, opw,
                                                    bn_g, bn_b, bn_m, bn_v, out);
        done += nch;
    }
}